// Round 1
// baseline (6775.072 us; speedup 1.0000x reference)
//
#include <hip/hip_runtime.h>

typedef short v8s __attribute__((ext_vector_type(8)));
typedef float v4f __attribute__((ext_vector_type(4)));
typedef unsigned short u16;

#define DI __device__ __forceinline__

constexpr int B = 32, S = 64, T = 48, E = 512, H = 1024, V = 32000;
constexpr int TP = T - 1;      // 47 prediction steps
constexpr int NCH = 500;       // 32000 / 64 vocab chunks
constexpr int NTG = 6;         // t-groups of 8 (last has 7)

DI u16 f2bf(float f) {
    unsigned u = __float_as_uint(f);
    unsigned r = (u + 0x7FFFu + ((u >> 16) & 1u)) >> 16;
    return (u16)r;
}
DI float bf2f(u16 h) { return __uint_as_float(((unsigned)h) << 16); }
DI v8s load8(const u16* p) { return *reinterpret_cast<const v8s*>(p); }

// ---------------- elementwise conversion f32 -> bf16 ----------------
__global__ __launch_bounds__(256) void k_cvt(const float* __restrict__ s,
                                             u16* __restrict__ d, int n4) {
    int i = blockIdx.x * 256 + threadIdx.x;
    if (i >= n4) return;
    float4 v = reinterpret_cast<const float4*>(s)[i];
    ushort4 o;
    o.x = f2bf(v.x); o.y = f2bf(v.y); o.z = f2bf(v.z); o.w = f2bf(v.w);
    reinterpret_cast<ushort4*>(d)[i] = o;
}

// ---------------- embedding gather: x[s][b][:] = emb[seq[b][s]] ----------------
__global__ __launch_bounds__(256) void k_embed(const int* __restrict__ seq, int seqstr,
                                               int nsteps, const float* __restrict__ emb,
                                               u16* __restrict__ out) {
    int i = blockIdx.x * 256 + threadIdx.x;
    int total = nsteps * B * (E / 4);
    if (i >= total) return;
    int q = i & 127;          // float4 index within row (E/4 = 128)
    int sb = i >> 7;
    int b = sb & 31;
    int s = sb >> 5;
    int tok = seq[b * seqstr + s];
    float4 v = reinterpret_cast<const float4*>(emb + (size_t)tok * E)[q];
    ushort4 o;
    o.x = f2bf(v.x); o.y = f2bf(v.y); o.z = f2bf(v.z); o.w = f2bf(v.w);
    reinterpret_cast<ushort4*>(out + ((size_t)(s * B + b)) * E)[q] = o;
}

// ---------------- reorder backward hidden states: ench_b[s*B+b] = hs_b[S-s] ----------------
__global__ __launch_bounds__(256) void k_enchb(const u16* __restrict__ hsb,
                                               u16* __restrict__ enchb) {
    int i = blockIdx.x * 256 + threadIdx.x;
    int total = S * B * (H / 8);
    if (i >= total) return;
    int j8 = i & 127;
    int sb = i >> 7;
    int b = sb & 31;
    int s = sb >> 5;
    const u16* src = hsb + ((size_t)((S - s) * B + b)) * H + j8 * 8;
    u16* dst = enchb + ((size_t)(s * B + b)) * H + j8 * 8;
    *reinterpret_cast<v8s*>(dst) = load8(src);
}

// ---------------- fused LSTM step ----------------
struct Seg { const u16* a; int astr; const u16* w; int wstr; int k; };
struct LstmP {
    Seg s1, s2, s3;
    const float* bih; const float* bhh;
    float* c; u16* hout;
};

__global__ __launch_bounds__(256) void k_lstm(LstmP p0, LstmP p1) {
    LstmP p = (blockIdx.y == 0) ? p0 : p1;
    const int tid = threadIdx.x;
    const int lane = tid & 63, wv = tid >> 6;   // wv = gate index 0..3
    const int l15 = lane & 15, lg = lane >> 4;
    const int j0 = blockIdx.x * 16;
    const int ncol = wv * H + j0 + l15;         // W row (gate column)
    v4f acc0 = {0.f, 0.f, 0.f, 0.f}, acc1 = {0.f, 0.f, 0.f, 0.f};
    for (int sgi = 0; sgi < 3; ++sgi) {
        Seg sg = (sgi == 0) ? p.s1 : (sgi == 1) ? p.s2 : p.s3;
        if (sg.k == 0) continue;
        const u16* wp = sg.w + (size_t)ncol * sg.wstr + 8 * lg;
        const u16* a0 = sg.a + (size_t)l15 * sg.astr + 8 * lg;
        const u16* a1 = a0 + (size_t)16 * sg.astr;
        for (int kb = 0; kb < sg.k; kb += 32) {
            v8s bf = load8(wp + kb);
            v8s af0 = load8(a0 + kb);
            v8s af1 = load8(a1 + kb);
            acc0 = __builtin_amdgcn_mfma_f32_16x16x32_bf16(af0, bf, acc0, 0, 0, 0);
            acc1 = __builtin_amdgcn_mfma_f32_16x16x32_bf16(af1, bf, acc1, 0, 0, 0);
        }
    }
    __shared__ float glds[4][32][16];
    for (int r = 0; r < 4; ++r) {
        glds[wv][lg * 4 + r][l15] = acc0[r];
        glds[wv][16 + lg * 4 + r][l15] = acc1[r];
    }
    __syncthreads();
    for (int idx = tid; idx < 512; idx += 256) {
        int b = idx >> 4, jl = idx & 15;
        int j = j0 + jl;
        float gi = glds[0][b][jl] + p.bih[j] + p.bhh[j];
        float gf = glds[1][b][jl] + p.bih[H + j] + p.bhh[H + j];
        float gg = glds[2][b][jl] + p.bih[2 * H + j] + p.bhh[2 * H + j];
        float go = glds[3][b][jl] + p.bih[3 * H + j] + p.bhh[3 * H + j];
        float si = 1.f / (1.f + expf(-gi));
        float sf = 1.f / (1.f + expf(-gf));
        float so = 1.f / (1.f + expf(-go));
        float tg = tanhf(gg);
        size_t ci = (size_t)b * H + j;
        float cn = sf * p.c[ci] + si * tg;
        p.c[ci] = cn;
        p.hout[ci] = f2bf(so * tanhf(cn));
    }
}

// ---------------- generic 2-segment MFMA GEMM: C = A1@W1^T + A2@W2^T ----------------
__global__ __launch_bounds__(256) void k_gemm(Seg s1, Seg s2,
                                              float* __restrict__ outf,
                                              u16* __restrict__ outb,
                                              int ostr, int storebf) {
    const int tid = threadIdx.x;
    const int lane = tid & 63, wv = tid >> 6;
    const int l15 = lane & 15, lg = lane >> 4;
    const int ncol = blockIdx.x * 64 + wv * 16 + l15;
    const int m0 = blockIdx.y * 16;
    v4f acc = {0.f, 0.f, 0.f, 0.f};
    for (int sgi = 0; sgi < 2; ++sgi) {
        Seg sg = (sgi == 0) ? s1 : s2;
        if (sg.k == 0) continue;
        const u16* wp = sg.w + (size_t)ncol * sg.wstr + 8 * lg;
        const u16* ap = sg.a + (size_t)(m0 + l15) * sg.astr + 8 * lg;
        for (int kb = 0; kb < sg.k; kb += 32) {
            v8s bf = load8(wp + kb);
            v8s af = load8(ap + kb);
            acc = __builtin_amdgcn_mfma_f32_16x16x32_bf16(af, bf, acc, 0, 0, 0);
        }
    }
    for (int r = 0; r < 4; ++r) {
        int row = m0 + lg * 4 + r;
        int col = blockIdx.x * 64 + wv * 16 + l15;
        if (storebf) outb[(size_t)row * ostr + col] = f2bf(acc[r]);
        else         outf[(size_t)row * ostr + col] = acc[r];
    }
}

// ---------------- per-step attention: scores -> softmax -> context ----------------
__global__ __launch_bounds__(256) void k_att(const u16* __restrict__ hnew,
                                             const float* __restrict__ encatt,
                                             const u16* __restrict__ hsf,
                                             const u16* __restrict__ enchb,
                                             u16* __restrict__ ctxb) {
    const int b = blockIdx.x;
    const int tid = threadIdx.x;
    __shared__ float hf[H];
    __shared__ float part[64][4];
    __shared__ float attw[64];
    for (int i = tid; i < H; i += 256) hf[i] = bf2f(hnew[(size_t)b * H + i]);
    __syncthreads();
    // scores[s] = h . enc_att[b][s]
    {
        int s = tid >> 2, q = tid & 3;
        const float4* att4 = reinterpret_cast<const float4*>(
            encatt + ((size_t)(s * B + b)) * H) + q * 64;
        int k0 = q * 256;
        float psum = 0.f;
        for (int x = 0; x < 64; ++x) {
            float4 a4 = att4[x];
            int k = k0 + x * 4;
            psum += a4.x * hf[k] + a4.y * hf[k + 1] + a4.z * hf[k + 2] + a4.w * hf[k + 3];
        }
        part[s][q] = psum;
    }
    __syncthreads();
    if (tid < 64) {
        int s = tid;
        float v = part[s][0] + part[s][1] + part[s][2] + part[s][3];
        float m = v;
        for (int o = 32; o; o >>= 1) m = fmaxf(m, __shfl_xor(m, o));
        float e = expf(v - m);
        float sum = e;
        for (int o = 32; o; o >>= 1) sum += __shfl_xor(sum, o);
        attw[s] = e / sum;
    }
    __syncthreads();
    // ctx[d] = sum_s attn[s] * enc_h[b][s][d], d in [0,2048)
    {
        int d0 = tid * 8;
        float a8[8];
        for (int e = 0; e < 8; ++e) a8[e] = 0.f;
        for (int s = 0; s < 64; ++s) {
            float w = attw[s];
            const u16* src = (d0 < H)
                ? hsf + ((size_t)((s + 1) * B + b)) * H + d0
                : enchb + ((size_t)(s * B + b)) * H + (d0 - H);
            v8s v = load8(src);
            for (int e = 0; e < 8; ++e) a8[e] += w * bf2f((u16)v[e]);
        }
        v8s o;
        for (int e = 0; e < 8; ++e) o[e] = (short)f2bf(a8[e]);
        *reinterpret_cast<v8s*>(ctxb + (size_t)b * 2 * H + d0) = o;
    }
}

// ---------------- projection chunk: logits + per-chunk (max, sumexp, gold) ----------------
__global__ __launch_bounds__(256) void k_proj(const u16* __restrict__ outs,
                                              const u16* __restrict__ wproj,
                                              const int* __restrict__ tgt,
                                              float* __restrict__ pmax,
                                              float* __restrict__ psum,
                                              float* __restrict__ pgold) {
    const int tid = threadIdx.x;
    const int lane = tid & 63, wv = tid >> 6;
    const int l15 = lane & 15, lg = lane >> 4;
    const int v0 = blockIdx.x * 64;
    const int ts = blockIdx.y * 8;
    const int te = (ts + 8 < TP) ? ts + 8 : TP;
    __shared__ float lgl[32][65];
    const u16* wb = wproj + (size_t)(v0 + wv * 16 + l15) * H + 8 * lg;
    for (int t = ts; t < te; ++t) {
        v4f acc0 = {0.f, 0.f, 0.f, 0.f}, acc1 = {0.f, 0.f, 0.f, 0.f};
        const u16* ab = outs + ((size_t)t * 32 + l15) * H + 8 * lg;
        for (int kb = 0; kb < H; kb += 32) {
            v8s wf = load8(wb + kb);
            v8s a0 = load8(ab + kb);
            v8s a1 = load8(ab + (size_t)16 * H + kb);
            acc0 = __builtin_amdgcn_mfma_f32_16x16x32_bf16(a0, wf, acc0, 0, 0, 0);
            acc1 = __builtin_amdgcn_mfma_f32_16x16x32_bf16(a1, wf, acc1, 0, 0, 0);
        }
        for (int r = 0; r < 4; ++r) {
            lgl[lg * 4 + r][wv * 16 + l15] = acc0[r];
            lgl[16 + lg * 4 + r][wv * 16 + l15] = acc1[r];
        }
        __syncthreads();
        if (tid < 32) {
            int b = tid;
            float m = -1e30f;
            for (int x = 0; x < 64; ++x) m = fmaxf(m, lgl[b][x]);
            float ss = 0.f;
            for (int x = 0; x < 64; ++x) ss += expf(lgl[b][x] - m);
            int gi = tgt[b * T + t + 1];
            float gv = (gi >= v0 && gi < v0 + 64) ? lgl[b][gi - v0] : 0.f;
            size_t idx = ((size_t)t * NCH + blockIdx.x) * 32 + b;
            pmax[idx] = m; psum[idx] = ss; pgold[idx] = gv;
        }
        __syncthreads();
    }
}

// ---------------- combine chunks -> logP[t][b] ----------------
__global__ __launch_bounds__(256) void k_lse(const float* __restrict__ pmax,
                                             const float* __restrict__ psum,
                                             const float* __restrict__ pgold,
                                             float* __restrict__ logP) {
    int item = blockIdx.x * 4 + (threadIdx.x >> 6);
    int lane = threadIdx.x & 63;
    if (item >= TP * 32) return;
    int t = item >> 5, b = item & 31;
    float m = -1e30f, g = 0.f;
    for (int c = lane; c < NCH; c += 64) {
        size_t idx = ((size_t)t * NCH + c) * 32 + b;
        m = fmaxf(m, pmax[idx]);
        g += pgold[idx];
    }
    for (int o = 32; o; o >>= 1) m = fmaxf(m, __shfl_xor(m, o));
    float s = 0.f;
    for (int c = lane; c < NCH; c += 64) {
        size_t idx = ((size_t)t * NCH + c) * 32 + b;
        s += psum[idx] * expf(pmax[idx] - m);
    }
    for (int o = 32; o; o >>= 1) { s += __shfl_xor(s, o); g += __shfl_xor(g, o); }
    if (lane == 0) logP[item] = g - (m + logf(s));
}

__global__ __launch_bounds__(64) void k_final(const float* __restrict__ logP,
                                              float* __restrict__ out) {
    int b = threadIdx.x;
    if (b < 32) {
        float s = 0.f;
        for (int t = 0; t < TP; ++t) s += logP[t * 32 + b];
        out[b] = s;
    }
}

// ================= host =================
extern "C" void kernel_launch(void* const* d_in, const int* in_sizes, int n_in,
                              void* d_out, int out_size, void* d_ws, size_t ws_size,
                              hipStream_t stream) {
    const int*   seq_in  = (const int*)d_in[0];
    const int*   seq_tgt = (const int*)d_in[1];
    const float* src_emb = (const float*)d_in[2];
    const float* tgt_emb = (const float*)d_in[3];
    const float* eWihF = (const float*)d_in[4];
    const float* eWhhF = (const float*)d_in[5];
    const float* eBihF = (const float*)d_in[6];
    const float* eBhhF = (const float*)d_in[7];
    const float* eWihB = (const float*)d_in[8];
    const float* eWhhB = (const float*)d_in[9];
    const float* eBihB = (const float*)d_in[10];
    const float* eBhhB = (const float*)d_in[11];
    const float* dWih  = (const float*)d_in[12];
    const float* dWhh  = (const float*)d_in[13];
    const float* dBih  = (const float*)d_in[14];
    const float* dBhh  = (const float*)d_in[15];
    const float* WinH  = (const float*)d_in[16];
    const float* WinC  = (const float*)d_in[17];
    const float* Watt  = (const float*)d_in[18];
    const float* Wcomb = (const float*)d_in[19];
    const float* Wproj = (const float*)d_in[20];

    char* ws = (char*)d_ws;
    size_t off = 0;
    auto alloc = [&](size_t bytes) -> char* {
        off = (off + 255) & ~(size_t)255;
        char* p = ws + off;
        off += bytes;
        return p;
    };
    const size_t G4 = 4 * (size_t)H;
    // bf16 weights
    u16* wihf = (u16*)alloc(G4 * E * 2);
    u16* whhf = (u16*)alloc(G4 * H * 2);
    u16* wihb = (u16*)alloc(G4 * E * 2);
    u16* whhb = (u16*)alloc(G4 * H * 2);
    u16* dwih = (u16*)alloc(G4 * (E + H) * 2);
    u16* dwhh = (u16*)alloc(G4 * H * 2);
    u16* winh = (u16*)alloc((size_t)H * 2 * H * 2);
    u16* winc = (u16*)alloc((size_t)H * 2 * H * 2);
    u16* watt = (u16*)alloc((size_t)H * 2 * H * 2);
    u16* wcmb = (u16*)alloc((size_t)H * 3 * H * 2);
    u16* wprj = (u16*)alloc((size_t)V * H * 2);
    // bf16 activations
    u16* xsrc  = (u16*)alloc((size_t)S * B * E * 2);
    u16* xtgt  = (u16*)alloc((size_t)T * B * E * 2);
    u16* hsf   = (u16*)alloc((size_t)(S + 1) * B * H * 2);
    u16* hsb   = (u16*)alloc((size_t)(S + 1) * B * H * 2);
    u16* enchb = (u16*)alloc((size_t)S * B * H * 2);
    u16* dech  = (u16*)alloc((size_t)2 * B * H * 2);
    u16* outsb = (u16*)alloc((size_t)T * B * H * 2);
    u16* ctxb  = (u16*)alloc((size_t)B * 2 * H * 2);
    u16* lcbf  = (u16*)alloc((size_t)2 * B * H * 2);
    u16* zeros = (u16*)alloc((size_t)B * H * 2);
    // f32 buffers
    float* cf    = (float*)alloc((size_t)B * H * 4);
    float* cb    = (float*)alloc((size_t)B * H * 4);   // contiguous after cf
    float* decc  = (float*)alloc((size_t)B * H * 4);
    float* encat = (float*)alloc((size_t)S * B * H * 4);
    float* pmax  = (float*)alloc((size_t)TP * NCH * 32 * 4);
    float* psum  = (float*)alloc((size_t)TP * NCH * 32 * 4);
    float* pgold = (float*)alloc((size_t)TP * NCH * 32 * 4);
    float* logP  = (float*)alloc((size_t)TP * 32 * 4);
    (void)ws_size; (void)in_sizes; (void)n_in; (void)out_size;

    // zero-init recurrent state + zeros buffer
    hipMemsetAsync(cf, 0, (size_t)2 * B * H * 4, stream);            // cf + cb
    hipMemsetAsync(hsf, 0, (size_t)B * H * 2, stream);               // h0 fwd
    hipMemsetAsync(hsb, 0, (size_t)B * H * 2, stream);               // h0 bwd
    hipMemsetAsync(zeros, 0, (size_t)B * H * 2, stream);             // prev_out t=0

    auto cvt = [&](const float* s, u16* d, size_t n) {
        int n4 = (int)(n / 4);
        k_cvt<<<dim3((n4 + 255) / 256), dim3(256), 0, stream>>>(s, d, n4);
    };
    cvt(eWihF, wihf, G4 * E);
    cvt(eWhhF, whhf, G4 * H);
    cvt(eWihB, wihb, G4 * E);
    cvt(eWhhB, whhb, G4 * H);
    cvt(dWih,  dwih, G4 * (E + H));
    cvt(dWhh,  dwhh, G4 * H);
    cvt(WinH,  winh, (size_t)H * 2 * H);
    cvt(WinC,  winc, (size_t)H * 2 * H);
    cvt(Watt,  watt, (size_t)H * 2 * H);
    cvt(Wcomb, wcmb, (size_t)H * 3 * H);
    cvt(Wproj, wprj, (size_t)V * H);

    // embeddings
    k_embed<<<dim3((S * B * (E / 4) + 255) / 256), dim3(256), 0, stream>>>(
        seq_in, S, S, src_emb, xsrc);
    k_embed<<<dim3((T * B * (E / 4) + 255) / 256), dim3(256), 0, stream>>>(
        seq_tgt, T, T, tgt_emb, xtgt);

    // ---------- bidirectional encoder ----------
    const size_t slot = (size_t)B * H;   // elements per h-slot
    for (int s = 0; s < S; ++s) {
        LstmP pf, pb;
        pf.s1 = Seg{xsrc + (size_t)s * B * E, E, wihf, E, E};
        pf.s2 = Seg{hsf + (size_t)s * slot, H, whhf, H, H};
        pf.s3 = Seg{nullptr, 0, nullptr, 0, 0};
        pf.bih = eBihF; pf.bhh = eBhhF; pf.c = cf;
        pf.hout = hsf + (size_t)(s + 1) * slot;
        pb.s1 = Seg{xsrc + (size_t)(S - 1 - s) * B * E, E, wihb, E, E};
        pb.s2 = Seg{hsb + (size_t)s * slot, H, whhb, H, H};
        pb.s3 = Seg{nullptr, 0, nullptr, 0, 0};
        pb.bih = eBihB; pb.bhh = eBhhB; pb.c = cb;
        pb.hout = hsb + (size_t)(s + 1) * slot;
        k_lstm<<<dim3(64, 2), dim3(256), 0, stream>>>(pf, pb);
    }

    // reorder backward states for (s*B+b) row addressing
    k_enchb<<<dim3((S * B * (H / 8) + 255) / 256), dim3(256), 0, stream>>>(hsb, enchb);

    // bf16 copies of final cell states (cf,cb contiguous -> lcbf)
    cvt(cf, lcbf, (size_t)2 * B * H);

    // decoder init: h0 = [hf|hb] @ WinH^T (bf16 out), c0 = [cf|cb] @ WinC^T (f32 out)
    {
        Seg a1{hsf + (size_t)S * slot, H, winh, 2 * H, H};
        Seg a2{hsb + (size_t)S * slot, H, winh + H, 2 * H, H};
        k_gemm<<<dim3(16, 2), dim3(256), 0, stream>>>(a1, a2, nullptr, dech, H, 1);
        Seg c1{lcbf, H, winc, 2 * H, H};
        Seg c2{lcbf + slot, H, winc + H, 2 * H, H};
        k_gemm<<<dim3(16, 2), dim3(256), 0, stream>>>(c1, c2, decc, nullptr, H, 0);
    }
    // enc_att = enc_h @ Watt^T  (rows r = s*B+b), f32 out
    {
        Seg a1{hsf + slot, H, watt, 2 * H, H};
        Seg a2{enchb, H, watt + H, 2 * H, H};
        k_gemm<<<dim3(16, 128), dim3(256), 0, stream>>>(a1, a2, encat, nullptr, H, 0);
    }

    // ---------- attention decoder ----------
    for (int t = 0; t < T; ++t) {
        u16* hin  = dech + (size_t)(t & 1) * slot;
        u16* hout = dech + (size_t)((t + 1) & 1) * slot;
        const u16* prev = (t == 0) ? zeros : outsb + (size_t)(t - 1) * slot;
        LstmP pd;
        pd.s1 = Seg{xtgt + (size_t)t * B * E, E, dwih, E + H, E};
        pd.s2 = Seg{prev, H, dwih + E, E + H, H};
        pd.s3 = Seg{hin, H, dwhh, H, H};
        pd.bih = dBih; pd.bhh = dBhh; pd.c = decc; pd.hout = hout;
        k_lstm<<<dim3(64, 1), dim3(256), 0, stream>>>(pd, pd);
        k_att<<<dim3(32), dim3(256), 0, stream>>>(hout, encat, hsf, enchb, ctxb);
        Seg m1{hout, H, wcmb, 3 * H, H};
        Seg m2{ctxb, 2 * H, wcmb + H, 3 * H, 2 * H};
        k_gemm<<<dim3(16, 2), dim3(256), 0, stream>>>(m1, m2, nullptr,
                                                      outsb + (size_t)t * slot, H, 1);
    }

    // ---------- vocab projection + log-softmax gather ----------
    k_proj<<<dim3(NCH, NTG), dim3(256), 0, stream>>>(outsb, wprj, seq_tgt,
                                                     pmax, psum, pgold);
    k_lse<<<dim3((TP * 32) / 4), dim3(256), 0, stream>>>(pmax, psum, pgold, logP);
    k_final<<<dim3(1), dim3(64), 0, stream>>>(logP, (float*)d_out);
}

// Round 2
// 2880.788 us; speedup vs baseline: 2.3518x; 2.3518x over previous
//
#include <hip/hip_runtime.h>

typedef short v8s __attribute__((ext_vector_type(8)));
typedef float v4f __attribute__((ext_vector_type(4)));
typedef unsigned short u16;

#define DI __device__ __forceinline__

constexpr int B = 32, S = 64, T = 48, E = 512, H = 1024, V = 32000;
constexpr int TP = T - 1;        // 47 prediction steps
constexpr int MROWS = TP * B;    // 1504 valid proj rows
constexpr int PM = 1536;         // padded proj M (12 tiles of 128)
constexpr int NCH = 250;         // 32000 / 128 vocab chunks

DI u16 f2bf(float f) {
    unsigned u = __float_as_uint(f);
    unsigned r = (u + 0x7FFFu + ((u >> 16) & 1u)) >> 16;
    return (u16)r;
}
DI float bf2f(u16 h) { return __uint_as_float(((unsigned)h) << 16); }
DI v8s load8(const u16* p) { return *reinterpret_cast<const v8s*>(p); }

typedef __attribute__((address_space(1))) const unsigned int gu32;
typedef __attribute__((address_space(3))) unsigned int lu32;
DI void gload_lds16(const u16* g, u16* l) {
    __builtin_amdgcn_global_load_lds((gu32*)g, (lu32*)l, 16, 0, 0);
}

// ---------------- elementwise conversion f32 -> bf16 ----------------
__global__ __launch_bounds__(256) void k_cvt(const float* __restrict__ s,
                                             u16* __restrict__ d, int n4) {
    int i = blockIdx.x * 256 + threadIdx.x;
    if (i >= n4) return;
    float4 v = reinterpret_cast<const float4*>(s)[i];
    ushort4 o;
    o.x = f2bf(v.x); o.y = f2bf(v.y); o.z = f2bf(v.z); o.w = f2bf(v.w);
    reinterpret_cast<ushort4*>(d)[i] = o;
}

// ---------------- embedding gather ----------------
__global__ __launch_bounds__(256) void k_embed(const int* __restrict__ seq, int seqstr,
                                               int nsteps, const float* __restrict__ emb,
                                               u16* __restrict__ out) {
    int i = blockIdx.x * 256 + threadIdx.x;
    int total = nsteps * B * (E / 4);
    if (i >= total) return;
    int q = i & 127;
    int sb = i >> 7;
    int b = sb & 31;
    int s = sb >> 5;
    int tok = seq[b * seqstr + s];
    float4 v = reinterpret_cast<const float4*>(emb + (size_t)tok * E)[q];
    ushort4 o;
    o.x = f2bf(v.x); o.y = f2bf(v.y); o.z = f2bf(v.z); o.w = f2bf(v.w);
    reinterpret_cast<ushort4*>(out + ((size_t)(s * B + b)) * E)[q] = o;
}

// ---------------- build ench[b][s][2H] from hsf/hsb ----------------
__global__ __launch_bounds__(256) void k_ench(const u16* __restrict__ hsf,
                                              const u16* __restrict__ hsb,
                                              u16* __restrict__ ench) {
    int id = blockIdx.x * 256 + threadIdx.x;       // 32*64*256 total
    int d8 = id & 255; int s = (id >> 8) & 63; int b = id >> 14;
    int d0 = d8 * 8;
    const u16* src = (d0 < H) ? hsf + (((size_t)(s + 1) * B + b)) * H + d0
                              : hsb + (((size_t)(S - s) * B + b)) * H + (d0 - H);
    *reinterpret_cast<v8s*>(ench + ((size_t)b * S + s) * 2 * H + d0) = load8(src);
}

// ---------------- split-K fused LSTM gates ----------------
struct Seg { const u16* a; int astr; const u16* w; int wstr; int k; };
struct GP {
    Seg s1, s2, s3;
    const float* bih; const float* bhh;
    float* c; u16* hout;
    int ks;                     // K per wave = Ktot/8
};

__global__ __launch_bounds__(512) void k_gates(GP p0, GP p1) {
    GP p = (blockIdx.y == 0) ? p0 : p1;
    const int tid = threadIdx.x;
    const int wv = tid >> 6, lane = tid & 63;
    const int l15 = lane & 15, lg = lane >> 4;
    const int j0 = blockIdx.x * 4;
    const int gate = l15 >> 2, jl = l15 & 3;
    const int wrow = gate * H + j0 + jl;
    const int k0 = wv * p.ks, k1 = k0 + p.ks;
    v4f acc0 = {0.f, 0.f, 0.f, 0.f}, acc1 = {0.f, 0.f, 0.f, 0.f};
    int base = 0;
    auto doseg = [&](const Seg& sg) {
        if (sg.k == 0) return;
        int s0 = k0 > base ? k0 : base;
        int send = base + sg.k;
        int s1 = k1 < send ? k1 : send;
        const u16* wp = sg.w + (size_t)wrow * sg.wstr + 8 * lg;
        const u16* a0p = sg.a + (size_t)l15 * sg.astr + 8 * lg;
        const u16* a1p = sg.a + (size_t)(16 + l15) * sg.astr + 8 * lg;
        #pragma unroll 2
        for (int k = s0; k < s1; k += 32) {
            int kl = k - base;
            v8s bf = load8(wp + kl);
            v8s af0 = load8(a0p + kl);
            v8s af1 = load8(a1p + kl);
            acc0 = __builtin_amdgcn_mfma_f32_16x16x32_bf16(af0, bf, acc0, 0, 0, 0);
            acc1 = __builtin_amdgcn_mfma_f32_16x16x32_bf16(af1, bf, acc1, 0, 0, 0);
        }
        base += sg.k;
    };
    doseg(p.s1); doseg(p.s2); doseg(p.s3);

    __shared__ float g[8][32][16];
    #pragma unroll
    for (int r = 0; r < 4; ++r) {
        g[wv][lg * 4 + r][l15] = acc0[r];
        g[wv][16 + lg * 4 + r][l15] = acc1[r];
    }
    __syncthreads();
    if (tid < 128) {
        int b = tid >> 2, jj = tid & 3;
        float gi = 0.f, gf = 0.f, gg = 0.f, go = 0.f;
        #pragma unroll
        for (int w = 0; w < 8; ++w) {
            gi += g[w][b][jj];
            gf += g[w][b][4 + jj];
            gg += g[w][b][8 + jj];
            go += g[w][b][12 + jj];
        }
        int j = j0 + jj;
        gi += p.bih[j] + p.bhh[j];
        gf += p.bih[H + j] + p.bhh[H + j];
        gg += p.bih[2 * H + j] + p.bhh[2 * H + j];
        go += p.bih[3 * H + j] + p.bhh[3 * H + j];
        float si = 1.f / (1.f + expf(-gi));
        float sf = 1.f / (1.f + expf(-gf));
        float so = 1.f / (1.f + expf(-go));
        float tg = tanhf(gg);
        size_t ci = (size_t)b * H + j;
        float cn = sf * p.c[ci] + si * tg;
        p.c[ci] = cn;
        p.hout[ci] = f2bf(so * tanhf(cn));
    }
}

// ---------------- split-K small GEMM (M=32): out = A1@W1^T + A2@W2^T ----------------
__global__ __launch_bounds__(512) void k_mm(Seg s1, Seg s2, float* __restrict__ outf,
                                            u16* __restrict__ outb, int ostr, int ks) {
    const int tid = threadIdx.x;
    const int wv = tid >> 6, lane = tid & 63;
    const int l15 = lane & 15, lg = lane >> 4;
    const int wrow = blockIdx.x * 16 + l15;
    const int k0 = wv * ks, k1 = k0 + ks;
    v4f acc0 = {0.f, 0.f, 0.f, 0.f}, acc1 = {0.f, 0.f, 0.f, 0.f};
    int base = 0;
    auto doseg = [&](const Seg& sg) {
        if (sg.k == 0) return;
        int s0 = k0 > base ? k0 : base;
        int send = base + sg.k;
        int s1e = k1 < send ? k1 : send;
        const u16* wp = sg.w + (size_t)wrow * sg.wstr + 8 * lg;
        const u16* a0p = sg.a + (size_t)l15 * sg.astr + 8 * lg;
        const u16* a1p = sg.a + (size_t)(16 + l15) * sg.astr + 8 * lg;
        #pragma unroll 2
        for (int k = s0; k < s1e; k += 32) {
            int kl = k - base;
            v8s bf = load8(wp + kl);
            v8s af0 = load8(a0p + kl);
            v8s af1 = load8(a1p + kl);
            acc0 = __builtin_amdgcn_mfma_f32_16x16x32_bf16(af0, bf, acc0, 0, 0, 0);
            acc1 = __builtin_amdgcn_mfma_f32_16x16x32_bf16(af1, bf, acc1, 0, 0, 0);
        }
        base += sg.k;
    };
    doseg(s1); doseg(s2);

    __shared__ float g[8][32][16];
    #pragma unroll
    for (int r = 0; r < 4; ++r) {
        g[wv][lg * 4 + r][l15] = acc0[r];
        g[wv][16 + lg * 4 + r][l15] = acc1[r];
    }
    __syncthreads();
    {
        int b = tid >> 4, cl = tid & 15;
        float v = 0.f;
        #pragma unroll
        for (int w = 0; w < 8; ++w) v += g[w][b][cl];
        int col = blockIdx.x * 16 + cl;
        if (outb) outb[(size_t)b * ostr + col] = f2bf(v);
        else      outf[(size_t)b * ostr + col] = v;
    }
}

// ---------------- generic MFMA GEMM (kept for one-time encatt) ----------------
__global__ __launch_bounds__(256) void k_gemm(Seg s1, Seg s2,
                                              float* __restrict__ outf,
                                              u16* __restrict__ outb,
                                              int ostr, int storebf) {
    const int tid = threadIdx.x;
    const int lane = tid & 63, wv = tid >> 6;
    const int l15 = lane & 15, lg = lane >> 4;
    const int ncol = blockIdx.x * 64 + wv * 16 + l15;
    const int m0 = blockIdx.y * 16;
    v4f acc = {0.f, 0.f, 0.f, 0.f};
    for (int sgi = 0; sgi < 2; ++sgi) {
        Seg sg = (sgi == 0) ? s1 : s2;
        if (sg.k == 0) continue;
        const u16* wp = sg.w + (size_t)ncol * sg.wstr + 8 * lg;
        const u16* ap = sg.a + (size_t)(m0 + l15) * sg.astr + 8 * lg;
        for (int kb = 0; kb < sg.k; kb += 32) {
            v8s bf = load8(wp + kb);
            v8s af = load8(ap + kb);
            acc = __builtin_amdgcn_mfma_f32_16x16x32_bf16(af, bf, acc, 0, 0, 0);
        }
    }
    for (int r = 0; r < 4; ++r) {
        int row = m0 + lg * 4 + r;
        int col = blockIdx.x * 64 + wv * 16 + l15;
        if (storebf) outb[(size_t)row * ostr + col] = f2bf(acc[r]);
        else         outf[(size_t)row * ostr + col] = acc[r];
    }
}

// ---------------- per-step attention (bf16 batch-major inputs) ----------------
__global__ __launch_bounds__(256) void k_att(const u16* __restrict__ hnew,
                                             const u16* __restrict__ encatt,
                                             const u16* __restrict__ ench,
                                             u16* __restrict__ ctxb) {
    const int b = blockIdx.x;
    const int tid = threadIdx.x;
    __shared__ float hf[4 * 260];
    __shared__ float part[64][4];
    __shared__ float attw[64];
    for (int i = tid; i < H; i += 256)
        hf[(i >> 8) * 260 + (i & 255)] = bf2f(hnew[(size_t)b * H + i]);
    __syncthreads();
    {
        int s = tid >> 2, q = tid & 3;
        const u16* ap = encatt + ((size_t)b * S + s) * H + q * 256;
        const float* hq = hf + q * 260;
        float ps = 0.f;
        #pragma unroll
        for (int x = 0; x < 32; ++x) {
            v8s v = load8(ap + x * 8);
            #pragma unroll
            for (int e = 0; e < 8; ++e) ps += bf2f((u16)v[e]) * hq[x * 8 + e];
        }
        part[s][q] = ps;
    }
    __syncthreads();
    if (tid < 64) {
        float v = part[tid][0] + part[tid][1] + part[tid][2] + part[tid][3];
        float m = v;
        #pragma unroll
        for (int o = 32; o; o >>= 1) m = fmaxf(m, __shfl_xor(m, o));
        float e = expf(v - m), sum = e;
        #pragma unroll
        for (int o = 32; o; o >>= 1) sum += __shfl_xor(sum, o);
        attw[tid] = e / sum;
    }
    __syncthreads();
    {
        int d0 = tid * 8;
        float a8[8];
        #pragma unroll
        for (int e = 0; e < 8; ++e) a8[e] = 0.f;
        for (int s2 = 0; s2 < 64; ++s2) {
            float w = attw[s2];
            v8s v = load8(ench + ((size_t)b * S + s2) * 2 * H + d0);
            #pragma unroll
            for (int e = 0; e < 8; ++e) a8[e] += w * bf2f((u16)v[e]);
        }
        v8s o;
        #pragma unroll
        for (int e = 0; e < 8; ++e) o[e] = (short)f2bf(a8[e]);
        *reinterpret_cast<v8s*>(ctxb + (size_t)b * 2 * H + d0) = o;
    }
}

// ---------------- tiled projection GEMM + fused softmax partials ----------------
// BM=BN=128, BK=64, 256 threads (4 waves 2x2), grid 3000 = 12 mt x 250 nt
__global__ __launch_bounds__(256) void k_proj(const u16* __restrict__ A,
                                              const u16* __restrict__ W,
                                              const int* __restrict__ tgt,
                                              float* __restrict__ pmax,
                                              float* __restrict__ psum,
                                              float* __restrict__ pgold) {
    __shared__ __align__(16) u16 As[128 * 64];
    __shared__ __align__(16) u16 Bs[128 * 64];
    __shared__ float red[128][2][3];
    const int tid = threadIdx.x;
    const int lane = tid & 63, wv = tid >> 6;
    const int l15 = lane & 15, lg = lane >> 4;
    const int wr = wv >> 1, wc = wv & 1;
    // XCD-aware remap: 3000 = 8 * 375, m fastest within each XCD chunk
    int id = blockIdx.x;
    int orig = (id & 7) * 375 + (id >> 3);
    int nt = orig / 12, mt = orig % 12;
    const int m0 = mt * 128, n0 = nt * 128;
    const int srow = lane >> 3, sc = lane & 7;

    v4f acc[4][4];
    #pragma unroll
    for (int i = 0; i < 4; ++i)
        #pragma unroll
        for (int j = 0; j < 4; ++j) acc[i][j] = v4f{0.f, 0.f, 0.f, 0.f};

    for (int kt = 0; kt < 16; ++kt) {
        const int kb = kt * 64;
        #pragma unroll
        for (int i = 0; i < 4; ++i) {
            int chunk = wv * 4 + i;
            int row = chunk * 8 + srow;
            int csw = (sc ^ (row & 7)) << 3;
            gload_lds16(A + (size_t)(m0 + row) * 1024 + kb + csw, As + chunk * 512);
            gload_lds16(W + (size_t)(n0 + row) * 1024 + kb + csw, Bs + chunk * 512);
        }
        __syncthreads();
        #pragma unroll
        for (int kk = 0; kk < 2; ++kk) {
            int sw = (((kk << 2) | lg) ^ (l15 & 7)) << 3;
            v8s af[4], bfv[4];
            #pragma unroll
            for (int mi = 0; mi < 4; ++mi)
                af[mi] = load8(As + (wr * 64 + mi * 16 + l15) * 64 + sw);
            #pragma unroll
            for (int ni = 0; ni < 4; ++ni)
                bfv[ni] = load8(Bs + (wc * 64 + ni * 16 + l15) * 64 + sw);
            #pragma unroll
            for (int mi = 0; mi < 4; ++mi)
                #pragma unroll
                for (int ni = 0; ni < 4; ++ni)
                    acc[mi][ni] = __builtin_amdgcn_mfma_f32_16x16x32_bf16(
                        af[mi], bfv[ni], acc[mi][ni], 0, 0, 0);
        }
        __syncthreads();
    }
    // per-row partials over this block's 128 cols
    #pragma unroll
    for (int mi = 0; mi < 4; ++mi) {
        #pragma unroll
        for (int rr = 0; rr < 4; ++rr) {
            int lrow = wr * 64 + mi * 16 + lg * 4 + rr;
            int grow = m0 + lrow;
            float vmax = -1e30f;
            #pragma unroll
            for (int ni = 0; ni < 4; ++ni) vmax = fmaxf(vmax, acc[mi][ni][rr]);
            #pragma unroll
            for (int x = 1; x < 16; x <<= 1) vmax = fmaxf(vmax, __shfl_xor(vmax, x));
            float se = 0.f;
            #pragma unroll
            for (int ni = 0; ni < 4; ++ni) se += expf(acc[mi][ni][rr] - vmax);
            #pragma unroll
            for (int x = 1; x < 16; x <<= 1) se += __shfl_xor(se, x);
            int t = grow >> 5, b = grow & 31;
            int g = (grow < MROWS) ? tgt[b * T + t + 1] : -1;
            float gv = 0.f;
            #pragma unroll
            for (int ni = 0; ni < 4; ++ni) {
                int col = n0 + wc * 64 + ni * 16 + l15;
                if (col == g) gv = acc[mi][ni][rr];
            }
            #pragma unroll
            for (int x = 1; x < 16; x <<= 1) gv += __shfl_xor(gv, x);
            if (l15 == 0) {
                red[lrow][wc][0] = vmax;
                red[lrow][wc][1] = se;
                red[lrow][wc][2] = gv;
            }
        }
    }
    __syncthreads();
    if (tid < 128) {
        int grow = m0 + tid;
        if (grow < MROWS) {
            float ma = red[tid][0][0], mb = red[tid][1][0];
            float M = fmaxf(ma, mb);
            float Sv = red[tid][0][1] * expf(ma - M) + red[tid][1][1] * expf(mb - M);
            float G = red[tid][0][2] + red[tid][1][2];
            size_t idx = (size_t)grow * NCH + nt;
            pmax[idx] = M; psum[idx] = Sv; pgold[idx] = G;
        }
    }
}

// ---------------- combine chunks -> logP[row] ----------------
__global__ __launch_bounds__(256) void k_lse(const float* __restrict__ pmax,
                                             const float* __restrict__ psum,
                                             const float* __restrict__ pgold,
                                             float* __restrict__ logP) {
    int item = blockIdx.x * 4 + (threadIdx.x >> 6);
    int lane = threadIdx.x & 63;
    if (item >= MROWS) return;
    float m = -1e30f, g = 0.f;
    for (int c = lane; c < NCH; c += 64) {
        size_t idx = (size_t)item * NCH + c;
        m = fmaxf(m, pmax[idx]);
        g += pgold[idx];
    }
    for (int o = 32; o; o >>= 1) m = fmaxf(m, __shfl_xor(m, o));
    float s = 0.f;
    for (int c = lane; c < NCH; c += 64) {
        size_t idx = (size_t)item * NCH + c;
        s += psum[idx] * expf(pmax[idx] - m);
    }
    for (int o = 32; o; o >>= 1) { s += __shfl_xor(s, o); g += __shfl_xor(g, o); }
    if (lane == 0) logP[item] = g - (m + logf(s));
}

__global__ __launch_bounds__(64) void k_final(const float* __restrict__ logP,
                                              float* __restrict__ out) {
    int b = threadIdx.x;
    if (b < 32) {
        float s = 0.f;
        for (int t = 0; t < TP; ++t) s += logP[t * 32 + b];
        out[b] = s;
    }
}

// ================= host =================
extern "C" void kernel_launch(void* const* d_in, const int* in_sizes, int n_in,
                              void* d_out, int out_size, void* d_ws, size_t ws_size,
                              hipStream_t stream) {
    const int*   seq_in  = (const int*)d_in[0];
    const int*   seq_tgt = (const int*)d_in[1];
    const float* src_emb = (const float*)d_in[2];
    const float* tgt_emb = (const float*)d_in[3];
    const float* eWihF = (const float*)d_in[4];
    const float* eWhhF = (const float*)d_in[5];
    const float* eBihF = (const float*)d_in[6];
    const float* eBhhF = (const float*)d_in[7];
    const float* eWihB = (const float*)d_in[8];
    const float* eWhhB = (const float*)d_in[9];
    const float* eBihB = (const float*)d_in[10];
    const float* eBhhB = (const float*)d_in[11];
    const float* dWih  = (const float*)d_in[12];
    const float* dWhh  = (const float*)d_in[13];
    const float* dBih  = (const float*)d_in[14];
    const float* dBhh  = (const float*)d_in[15];
    const float* WinH  = (const float*)d_in[16];
    const float* WinC  = (const float*)d_in[17];
    const float* Watt  = (const float*)d_in[18];
    const float* Wcomb = (const float*)d_in[19];
    const float* Wproj = (const float*)d_in[20];

    char* ws = (char*)d_ws;
    size_t off = 0;
    auto alloc = [&](size_t bytes) -> char* {
        off = (off + 255) & ~(size_t)255;
        char* p = ws + off;
        off += bytes;
        return p;
    };
    const size_t G4 = 4 * (size_t)H;
    // bf16 weights
    u16* wihf = (u16*)alloc(G4 * E * 2);
    u16* whhf = (u16*)alloc(G4 * H * 2);
    u16* wihb = (u16*)alloc(G4 * E * 2);
    u16* whhb = (u16*)alloc(G4 * H * 2);
    u16* dwih = (u16*)alloc(G4 * (E + H) * 2);
    u16* dwhh = (u16*)alloc(G4 * H * 2);
    u16* winh = (u16*)alloc((size_t)H * 2 * H * 2);
    u16* winc = (u16*)alloc((size_t)H * 2 * H * 2);
    u16* watt = (u16*)alloc((size_t)H * 2 * H * 2);
    u16* wcmb = (u16*)alloc((size_t)H * 3 * H * 2);
    u16* wprj = (u16*)alloc((size_t)V * H * 2);
    // bf16 activations
    u16* xsrc  = (u16*)alloc((size_t)S * B * E * 2);
    u16* xtgt  = (u16*)alloc((size_t)T * B * E * 2);
    u16* hsf   = (u16*)alloc((size_t)(S + 1) * B * H * 2);
    u16* hsb   = (u16*)alloc((size_t)(S + 1) * B * H * 2);
    u16* ench  = (u16*)alloc((size_t)B * S * 2 * H * 2);   // [b][s][2H]
    u16* encab = (u16*)alloc((size_t)B * S * H * 2);       // [b][s][H]
    u16* dech  = (u16*)alloc((size_t)2 * B * H * 2);
    u16* outsb = (u16*)alloc((size_t)PM * H * 2);          // padded to 1536 rows
    u16* ctxb  = (u16*)alloc((size_t)B * 2 * H * 2);
    u16* lcbf  = (u16*)alloc((size_t)2 * B * H * 2);
    u16* zeros = (u16*)alloc((size_t)B * H * 2);
    // f32 buffers
    float* cf    = (float*)alloc((size_t)B * H * 4);
    float* cb    = (float*)alloc((size_t)B * H * 4);   // contiguous after cf
    float* decc  = (float*)alloc((size_t)B * H * 4);
    float* pmax  = (float*)alloc((size_t)MROWS * NCH * 4);
    float* psum  = (float*)alloc((size_t)MROWS * NCH * 4);
    float* pgold = (float*)alloc((size_t)MROWS * NCH * 4);
    float* logP  = (float*)alloc((size_t)MROWS * 4);
    (void)ws_size; (void)in_sizes; (void)n_in; (void)out_size;

    hipMemsetAsync(cf, 0, (size_t)2 * B * H * 4, stream);   // cf + cb
    hipMemsetAsync(hsf, 0, (size_t)B * H * 2, stream);
    hipMemsetAsync(hsb, 0, (size_t)B * H * 2, stream);
    hipMemsetAsync(zeros, 0, (size_t)B * H * 2, stream);

    auto cvt = [&](const float* s, u16* d, size_t n) {
        int n4 = (int)(n / 4);
        k_cvt<<<dim3((n4 + 255) / 256), dim3(256), 0, stream>>>(s, d, n4);
    };
    cvt(eWihF, wihf, G4 * E);
    cvt(eWhhF, whhf, G4 * H);
    cvt(eWihB, wihb, G4 * E);
    cvt(eWhhB, whhb, G4 * H);
    cvt(dWih,  dwih, G4 * (E + H));
    cvt(dWhh,  dwhh, G4 * H);
    cvt(WinH,  winh, (size_t)H * 2 * H);
    cvt(WinC,  winc, (size_t)H * 2 * H);
    cvt(Watt,  watt, (size_t)H * 2 * H);
    cvt(Wcomb, wcmb, (size_t)H * 3 * H);
    cvt(Wproj, wprj, (size_t)V * H);

    k_embed<<<dim3((S * B * (E / 4) + 255) / 256), dim3(256), 0, stream>>>(
        seq_in, S, S, src_emb, xsrc);
    k_embed<<<dim3((T * B * (E / 4) + 255) / 256), dim3(256), 0, stream>>>(
        seq_tgt, T, T, tgt_emb, xtgt);

    // ---------- bidirectional encoder ----------
    const size_t slot = (size_t)B * H;
    for (int s = 0; s < S; ++s) {
        GP pf, pb;
        pf.s1 = Seg{xsrc + (size_t)s * B * E, E, wihf, E, E};
        pf.s2 = Seg{hsf + (size_t)s * slot, H, whhf, H, H};
        pf.s3 = Seg{nullptr, 0, nullptr, 0, 0};
        pf.bih = eBihF; pf.bhh = eBhhF; pf.c = cf;
        pf.hout = hsf + (size_t)(s + 1) * slot;
        pf.ks = (E + H) / 8;
        pb.s1 = Seg{xsrc + (size_t)(S - 1 - s) * B * E, E, wihb, E, E};
        pb.s2 = Seg{hsb + (size_t)s * slot, H, whhb, H, H};
        pb.s3 = Seg{nullptr, 0, nullptr, 0, 0};
        pb.bih = eBihB; pb.bhh = eBhhB; pb.c = cb;
        pb.hout = hsb + (size_t)(s + 1) * slot;
        pb.ks = (E + H) / 8;
        k_gates<<<dim3(H / 4, 2), dim3(512), 0, stream>>>(pf, pb);
    }

    // batch-major enc_h and enc_att (bf16)
    k_ench<<<dim3(B * S * (2 * H / 8) / 256), dim3(256), 0, stream>>>(hsf, hsb, ench);
    {
        Seg a1{ench, 2 * H, watt, 2 * H, 2 * H};
        Seg a2{nullptr, 0, nullptr, 0, 0};
        k_gemm<<<dim3(H / 64, B * S / 16), dim3(256), 0, stream>>>(a1, a2, nullptr,
                                                                   encab, H, 1);
    }

    cvt(cf, lcbf, (size_t)2 * B * H);   // [cf|cb] -> bf16

    // decoder init
    {
        Seg a1{hsf + (size_t)S * slot, H, winh, 2 * H, H};
        Seg a2{hsb + (size_t)S * slot, H, winh + H, 2 * H, H};
        k_mm<<<dim3(H / 16), dim3(512), 0, stream>>>(a1, a2, nullptr, dech, H, 2 * H / 8);
        Seg c1{lcbf, H, winc, 2 * H, H};
        Seg c2{lcbf + slot, H, winc + H, 2 * H, H};
        k_mm<<<dim3(H / 16), dim3(512), 0, stream>>>(c1, c2, decc, nullptr, H, 2 * H / 8);
    }

    // ---------- attention decoder ----------
    for (int t = 0; t < T; ++t) {
        u16* hin  = dech + (size_t)(t & 1) * slot;
        u16* hout = dech + (size_t)((t + 1) & 1) * slot;
        const u16* prev = (t == 0) ? zeros : outsb + (size_t)(t - 1) * slot;
        GP pd;
        pd.s1 = Seg{xtgt + (size_t)t * B * E, E, dwih, E + H, E};
        pd.s2 = Seg{prev, H, dwih + E, E + H, H};
        pd.s3 = Seg{hin, H, dwhh, H, H};
        pd.bih = dBih; pd.bhh = dBhh; pd.c = decc; pd.hout = hout;
        pd.ks = (E + H + H) / 8;
        k_gates<<<dim3(H / 4, 1), dim3(512), 0, stream>>>(pd, pd);
        k_att<<<dim3(32), dim3(256), 0, stream>>>(hout, encab, ench, ctxb);
        Seg m1{hout, H, wcmb, 3 * H, H};
        Seg m2{ctxb, 2 * H, wcmb + H, 3 * H, 2 * H};
        k_mm<<<dim3(H / 16), dim3(512), 0, stream>>>(m1, m2, nullptr,
                                                     outsb + (size_t)t * slot, H, 3 * H / 8);
    }

    // ---------- vocab projection + log-softmax ----------
    k_proj<<<dim3(3000), dim3(256), 0, stream>>>(outsb, wprj, seq_tgt, pmax, psum, pgold);
    k_lse<<<dim3((MROWS + 3) / 4), dim3(256), 0, stream>>>(pmax, psum, pgold, logP);
    k_final<<<dim3(1), dim3(64), 0, stream>>>(logP, (float*)d_out);
}